// Round 1
// baseline (1354.791 us; speedup 1.0000x reference)
//
#include <hip/hip_runtime.h>
#include <math.h>

#define EPS 1e-5f

// ---------- helpers ----------
__device__ __forceinline__ unsigned fenc(float x) {
    unsigned u = __float_as_uint(x);
    return (u & 0x80000000u) ? ~u : (u | 0x80000000u);
}
__device__ __forceinline__ float fdec(unsigned e) {
    return __uint_as_float((e & 0x80000000u) ? (e ^ 0x80000000u) : ~e);
}
#define ENC_NEG_INF 0x007FFFFFu  // fenc(-inf)

__device__ __forceinline__ float gelu_exact(float v) {
    return 0.5f * v * (1.0f + erff(v * 0.70710678118654752f));
}

// ---------- segment boundaries from sorted batch ----------
__global__ void seg_bounds_k(const int* __restrict__ batch, int N, int G, int* __restrict__ seg) {
    int i = blockIdx.x * blockDim.x + threadIdx.x;
    if (i >= N) return;
    int b = batch[i];
    if (i == 0) {
        for (int g = 0; g <= b; ++g) seg[g] = 0;
    } else {
        int pb = batch[i - 1];
        for (int g = pb + 1; g <= b; ++g) seg[g] = i;
    }
    if (i == N - 1) {
        for (int g = b + 1; g <= G; ++g) seg[g] = N;
    }
}

__global__ void fill_u32_k(unsigned* __restrict__ p, long n, unsigned val) {
    long i = (long)blockIdx.x * blockDim.x + threadIdx.x;
    if (i < n) p[i] = val;
}

// ---------- generic fp32 linear: out[N][M] = A[N][K] @ W[K][M] + bias ----------
template <int K, int M>
__global__ void linear_k(const float* __restrict__ A, const float* __restrict__ W,
                         const float* __restrict__ bias, float* __restrict__ outp, int nrows) {
    constexpr int ROWS = 32;
    constexpr int NG = 256 / M;     // thread groups (cols covered once each)
    constexpr int RPT = ROWS / NG;  // rows per thread
    __shared__ float lds[ROWS * K];
    int row0 = blockIdx.x * ROWS;
    int t = threadIdx.x;
    for (int idx = t; idx < ROWS * K; idx += 256) {
        int r = idx / K, c = idx % K;
        int row = row0 + r;
        lds[idx] = (row < nrows) ? A[(long)row * K + c] : 0.0f;
    }
    __syncthreads();
    int c = t % M, g = t / M;
    float acc[RPT];
    float bv = bias[c];
#pragma unroll
    for (int r = 0; r < RPT; ++r) acc[r] = bv;
    for (int k = 0; k < K; ++k) {
        float w = W[k * M + c];
#pragma unroll
        for (int r = 0; r < RPT; ++r) acc[r] += lds[(g * RPT + r) * K + k] * w;
    }
#pragma unroll
    for (int r = 0; r < RPT; ++r) {
        int row = row0 + g * RPT + r;
        if (row < nrows) outp[(long)row * M + c] = acc[r];
    }
}

// ---------- edge pass A: logits + segment max ----------
template <int HC_, int C_>
__global__ void edge_logit_k(const float* __restrict__ xl, const float* __restrict__ xr,
                             const float* __restrict__ att, const int* __restrict__ ei,
                             int E, int Etot, float* __restrict__ logit,
                             unsigned* __restrict__ nmax) {
    constexpr int EPB = 256 / HC_;
    constexpr int H_ = HC_ / C_;
    int t = threadIdx.x;
    int e = blockIdx.x * EPB + t / HC_;
    if (e >= Etot) return;
    int f = t % HC_;
    int src, dst;
    if (e < E) { src = ei[e]; dst = ei[E + e]; }
    else       { src = e - E; dst = src; }
    float v = xl[(long)src * HC_ + f] + xr[(long)dst * HC_ + f];
    v = (v > 0.0f) ? v : 0.2f * v;   // leaky_relu 0.2
    v *= att[f];                      // att flat: f = h*C + c
#pragma unroll
    for (int off = C_ / 2; off > 0; off >>= 1) v += __shfl_xor(v, off, C_);
    if ((f % C_) == 0) {
        int h = f / C_;
        logit[(long)e * H_ + h] = v;
        atomicMax(&nmax[(long)dst * H_ + h], fenc(v));
    }
}

// ---------- edge pass B: exp + denominator ----------
__global__ void edge_exp_k(const int* __restrict__ ei, int E, int Etot, int H_,
                           const unsigned* __restrict__ nmax, float* __restrict__ logit,
                           float* __restrict__ den) {
    long i = (long)blockIdx.x * blockDim.x + threadIdx.x;
    long tot = (long)Etot * H_;
    if (i >= tot) return;
    int e = (int)(i / H_);
    int h = (int)(i % H_);
    int dst = (e < E) ? ei[E + e] : (e - E);
    float m = fdec(nmax[(long)dst * H_ + h]);
    float ex = expf(logit[i] - m);
    logit[i] = ex;  // store exp in place
    atomicAdd(&den[(long)dst * H_ + h], ex);
}

// ---------- edge pass C: weighted aggregation ----------
template <int HC_, int C_>
__global__ void edge_aggr_k(const float* __restrict__ xl, const int* __restrict__ ei,
                            int E, int Etot, const float* __restrict__ exv,
                            const float* __restrict__ den, float* __restrict__ outp) {
    constexpr int EPB = 256 / HC_;
    constexpr int H_ = HC_ / C_;
    int t = threadIdx.x;
    int e = blockIdx.x * EPB + t / HC_;
    if (e >= Etot) return;
    int f = t % HC_;
    int src, dst;
    if (e < E) { src = ei[e]; dst = ei[E + e]; }
    else       { src = e - E; dst = src; }
    int h = f / C_;
    float alpha = exv[(long)e * H_ + h] / den[(long)dst * H_ + h];
    atomicAdd(&outp[(long)dst * HC_ + f], xl[(long)src * HC_ + f] * alpha);
}

// ---------- graph norm stats: one block per graph, blockDim = F ----------
__global__ void gn_stats_k(const float* __restrict__ x, const float* __restrict__ bias,
                           const float* __restrict__ ms, const int* __restrict__ seg, int F,
                           float* __restrict__ meanp, float* __restrict__ istdp) {
    int g = blockIdx.x, f = threadIdx.x;
    int s = seg[g], epos = seg[g + 1];
    int count = epos - s;
    float cnt = (float)max(count, 1);
    float bv = bias[f];
    float sum = 0.f;
    for (int n = s; n < epos; ++n) sum += x[(long)n * F + f];
    float mean = (sum + bv * (float)count) / cnt;  // mean of (x + bias); 0 if empty
    float mms = mean * ms[f];
    float s2 = 0.f;
    for (int n = s; n < epos; ++n) {
        float d = x[(long)n * F + f] + bv - mms;
        s2 += d * d;
    }
    float var = s2 / cnt;
    meanp[(long)g * F + f] = mean;
    istdp[(long)g * F + f] = 1.0f / sqrtf(var + EPS);
}

// ---------- graph norm apply + residual + exact GELU ----------
template <int F>
__global__ void gn_apply_k(const float* __restrict__ x, const float* __restrict__ bias,
                           const int* __restrict__ batch, const float* __restrict__ meanp,
                           const float* __restrict__ istdp, const float* __restrict__ w,
                           const float* __restrict__ b, const float* __restrict__ ms,
                           const float* __restrict__ res, float* __restrict__ h, long total) {
    long i = (long)blockIdx.x * blockDim.x + threadIdx.x;
    if (i >= total) return;
    int n = (int)(i / F), f = (int)(i % F);
    int g = batch[n];
    float xv = x[i] + bias[f];
    float o = w[f] * (xv - meanp[(long)g * F + f] * ms[f]) * istdp[(long)g * F + f] + b[f];
    h[i] = gelu_exact(o + res[i]);
}

// ---------- pooling + ego gate + MLP head (one block per graph) ----------
__global__ void pool_head_k(const float* __restrict__ h2, const int* __restrict__ seg,
                            const float* __restrict__ Weg, const float* __restrict__ beg,
                            const float* __restrict__ Wf1, const float* __restrict__ bf1,
                            const float* __restrict__ Wf2, const float* __restrict__ bf2,
                            float* __restrict__ outp) {
    int g = blockIdx.x, t = threadIdx.x;
    int s = seg[g], epos = seg[g + 1];
    int count = epos - s;
    __shared__ float ssum[8][32];
    __shared__ float smax[8][32];
    __shared__ float xfinal[96];  // [0..31]=x_root(mean), [32..95]=x_neigh
    __shared__ float emb[32];
    int f = t % 32, j = t / 32;
    float sum = 0.f, mx = -INFINITY;
    for (int n = s + j; n < epos; n += 8) {
        float v = h2[(long)n * 32 + f];
        sum += v;
        mx = fmaxf(mx, v);
    }
    ssum[j][f] = sum;
    smax[j][f] = mx;
    __syncthreads();
    if (t < 32) {
        float acs = 0.f, acm = -INFINITY;
        for (int jj = 0; jj < 8; ++jj) { acs += ssum[jj][t]; acm = fmaxf(acm, smax[jj][t]); }
        float mean = acs / (float)max(count, 1);
        float mxv = (count > 0) ? acm : 0.0f;
        xfinal[t] = mean;   // x_root
        smax[0][t] = mxv;   // stash max
    }
    __syncthreads();
    if (t < 64) {
        float acc = beg[t];
        for (int k = 0; k < 32; ++k) acc += xfinal[k] * Weg[k * 64 + t];
        float gate = 1.0f / (1.0f + expf(-acc));
        float val = (t < 32) ? xfinal[t] : smax[0][t - 32];
        xfinal[32 + t] = gate * val;  // writes [32..95]; reads were [0..31]
    }
    __syncthreads();
    if (t < 32) {
        float acc = bf1[t];
        for (int k = 0; k < 96; ++k) acc += xfinal[k] * Wf1[k * 32 + t];
        emb[t] = gelu_exact(acc);
    }
    __syncthreads();
    if (t < 32) {
        float v = emb[t] * Wf2[t];
#pragma unroll
        for (int off = 16; off > 0; off >>= 1) v += __shfl_xor(v, off, 32);
        if (t == 0) outp[g] = v + bf2[0];
    }
}

// ---------- launcher ----------
extern "C" void kernel_launch(void* const* d_in, const int* in_sizes, int n_in, void* d_out,
                              int out_size, void* d_ws, size_t ws_size, hipStream_t stream) {
    const float* x      = (const float*)d_in[0];
    const int*   ei     = (const int*)d_in[1];
    const int*   batch  = (const int*)d_in[2];
    const float* Wl1    = (const float*)d_in[3];
    const float* bl1    = (const float*)d_in[4];
    const float* Wr1    = (const float*)d_in[5];
    const float* br1    = (const float*)d_in[6];
    const float* att1   = (const float*)d_in[7];
    const float* bias1  = (const float*)d_in[8];
    const float* gn1_w  = (const float*)d_in[9];
    const float* gn1_b  = (const float*)d_in[10];
    const float* gn1_ms = (const float*)d_in[11];
    const float* Wl2    = (const float*)d_in[12];
    const float* bl2    = (const float*)d_in[13];
    const float* Wr2    = (const float*)d_in[14];
    const float* br2    = (const float*)d_in[15];
    const float* att2   = (const float*)d_in[16];
    const float* bias2  = (const float*)d_in[17];
    const float* gn2_w  = (const float*)d_in[18];
    const float* gn2_b  = (const float*)d_in[19];
    const float* gn2_ms = (const float*)d_in[20];
    const float* Wp1    = (const float*)d_in[21];
    const float* bp1    = (const float*)d_in[22];
    const float* Wp2    = (const float*)d_in[23];
    const float* bp2    = (const float*)d_in[24];
    const float* Weg    = (const float*)d_in[25];
    const float* beg    = (const float*)d_in[26];
    const float* Wf1    = (const float*)d_in[27];
    const float* bf1    = (const float*)d_in[28];
    const float* Wf2    = (const float*)d_in[29];
    const float* bf2    = (const float*)d_in[30];
    float* outp = (float*)d_out;

    const int N = in_sizes[2];
    const int E = in_sizes[1] / 2;
    const int Etot = E + N;
    const int G = out_size;
    constexpr int HC = 128, C = 32, H = 4;

    // workspace carve-out
    char* ws = (char*)d_ws;
    size_t off = 0;
    auto alloc = [&](size_t bytes) -> void* {
        void* p = ws + off;
        off += (bytes + 255) & ~(size_t)255;
        return p;
    };
    int*      seg    = (int*)alloc((size_t)(G + 1) * 4);
    float*    xl1    = (float*)alloc((size_t)N * HC * 4);
    float*    xr1    = (float*)alloc((size_t)N * HC * 4);
    float*    res1   = (float*)alloc((size_t)N * HC * 4);
    float*    out1   = (float*)alloc((size_t)N * HC * 4);
    float*    h1     = (float*)alloc((size_t)N * HC * 4);
    float*    logit1 = (float*)alloc((size_t)Etot * H * 4);
    unsigned* nmax1  = (unsigned*)alloc((size_t)N * H * 4);
    float*    den1   = (float*)alloc((size_t)N * H * 4);
    float*    mean1  = (float*)alloc((size_t)G * HC * 4);
    float*    istd1  = (float*)alloc((size_t)G * HC * 4);
    float*    xl2    = (float*)alloc((size_t)N * C * 4);
    float*    xr2    = (float*)alloc((size_t)N * C * 4);
    float*    res2   = (float*)alloc((size_t)N * C * 4);
    float*    out2   = (float*)alloc((size_t)N * C * 4);
    float*    h2     = (float*)alloc((size_t)N * C * 4);
    float*    logit2 = (float*)alloc((size_t)Etot * 4);
    unsigned* nmax2  = (unsigned*)alloc((size_t)N * 4);
    float*    den2   = (float*)alloc((size_t)N * 4);
    float*    mean2  = (float*)alloc((size_t)G * C * 4);
    float*    istd2  = (float*)alloc((size_t)G * C * 4);
    (void)ws_size; (void)n_in;

    // init
    seg_bounds_k<<<(N + 255) / 256, 256, 0, stream>>>(batch, N, G, seg);
    fill_u32_k<<<((long)N * H + 255) / 256, 256, 0, stream>>>(nmax1, (long)N * H, ENC_NEG_INF);
    fill_u32_k<<<((long)N + 255) / 256, 256, 0, stream>>>(nmax2, (long)N, ENC_NEG_INF);
    hipMemsetAsync(den1, 0, (size_t)N * H * 4, stream);
    hipMemsetAsync(den2, 0, (size_t)N * 4, stream);
    hipMemsetAsync(out1, 0, (size_t)N * HC * 4, stream);
    hipMemsetAsync(out2, 0, (size_t)N * C * 4, stream);

    // ---- layer 1 ----
    int gblk = (N + 31) / 32;
    linear_k<128, 128><<<gblk, 256, 0, stream>>>(x, Wl1, bl1, xl1, N);
    linear_k<128, 128><<<gblk, 256, 0, stream>>>(x, Wr1, br1, xr1, N);
    linear_k<128, 128><<<gblk, 256, 0, stream>>>(x, Wp1, bp1, res1, N);

    edge_logit_k<128, 32><<<(Etot + 1) / 2, 256, 0, stream>>>(xl1, xr1, att1, ei, E, Etot, logit1, nmax1);
    edge_exp_k<<<((long)Etot * H + 255) / 256, 256, 0, stream>>>(ei, E, Etot, H, nmax1, logit1, den1);
    edge_aggr_k<128, 32><<<(Etot + 1) / 2, 256, 0, stream>>>(xl1, ei, E, Etot, logit1, den1, out1);

    gn_stats_k<<<G, 128, 0, stream>>>(out1, bias1, gn1_ms, seg, 128, mean1, istd1);
    gn_apply_k<128><<<(int)(((long)N * 128 + 255) / 256), 256, 0, stream>>>(
        out1, bias1, batch, mean1, istd1, gn1_w, gn1_b, gn1_ms, res1, h1, (long)N * 128);

    // ---- layer 2 ----
    linear_k<128, 32><<<gblk, 256, 0, stream>>>(h1, Wl2, bl2, xl2, N);
    linear_k<128, 32><<<gblk, 256, 0, stream>>>(h1, Wr2, br2, xr2, N);
    linear_k<128, 32><<<gblk, 256, 0, stream>>>(h1, Wp2, bp2, res2, N);

    edge_logit_k<32, 32><<<(Etot + 7) / 8, 256, 0, stream>>>(xl2, xr2, att2, ei, E, Etot, logit2, nmax2);
    edge_exp_k<<<((long)Etot + 255) / 256, 256, 0, stream>>>(ei, E, Etot, 1, nmax2, logit2, den2);
    edge_aggr_k<32, 32><<<(Etot + 7) / 8, 256, 0, stream>>>(xl2, ei, E, Etot, logit2, den2, out2);

    gn_stats_k<<<G, 32, 0, stream>>>(out2, bias2, gn2_ms, seg, 32, mean2, istd2);
    gn_apply_k<32><<<(int)(((long)N * 32 + 255) / 256), 256, 0, stream>>>(
        out2, bias2, batch, mean2, istd2, gn2_w, gn2_b, gn2_ms, res2, h2, (long)N * 32);

    // ---- pooling + gate + head ----
    pool_head_k<<<G, 256, 0, stream>>>(h2, seg, Weg, beg, Wf1, bf1, Wf2, bf2, outp);
}

// Round 2
// 796.252 us; speedup vs baseline: 1.7015x; 1.7015x over previous
//
#include <hip/hip_runtime.h>
#include <math.h>

#define EPS 1e-5f

__device__ __forceinline__ float gelu_exact(float v) {
    return 0.5f * v * (1.0f + erff(v * 0.70710678118654752f));
}

// ---------- segment boundaries from sorted batch ----------
__global__ void seg_bounds_k(const int* __restrict__ batch, int N, int G, int* __restrict__ seg) {
    int i = blockIdx.x * blockDim.x + threadIdx.x;
    if (i >= N) return;
    int b = batch[i];
    if (i == 0) {
        for (int g = 0; g <= b; ++g) seg[g] = 0;
    } else {
        int pb = batch[i - 1];
        for (int g = pb + 1; g <= b; ++g) seg[g] = i;
    }
    if (i == N - 1) {
        for (int g = b + 1; g <= G; ++g) seg[g] = N;
    }
}

// ---------- CSR build: histogram over dst ----------
__global__ void hist_k(const int* __restrict__ ei, int E, int Etot, int* __restrict__ cnt) {
    int e = blockIdx.x * blockDim.x + threadIdx.x;
    if (e >= Etot) return;
    int dst = (e < E) ? ei[E + e] : (e - E);
    atomicAdd(&cnt[dst], 1);
}

// ---------- single-block scan: rowptr = exclusive prefix of cnt ----------
__global__ void scan_k(const int* __restrict__ cnt, int N, int* __restrict__ rowptr) {
    __shared__ int ts[1024];
    int t = threadIdx.x;
    int chunk = (N + 1023) / 1024;
    int s0 = t * chunk;
    int e0 = min(s0 + chunk, N);
    int sum = 0;
    for (int i = s0; i < e0; ++i) sum += cnt[i];
    ts[t] = sum;
    __syncthreads();
    for (int off = 1; off < 1024; off <<= 1) {
        int v = (t >= off) ? ts[t - off] : 0;
        __syncthreads();
        ts[t] += v;
        __syncthreads();
    }
    int run = (t > 0) ? ts[t - 1] : 0;
    for (int i = s0; i < e0; ++i) {
        rowptr[i] = run;
        run += cnt[i];
    }
    if (t == 1023) rowptr[N] = ts[1023];
}

// ---------- CSR scatter: store src per slot ----------
__global__ void scatter_k(const int* __restrict__ ei, int E, int Etot,
                          const int* __restrict__ rowptr, int* __restrict__ cur,
                          int* __restrict__ esrc) {
    int e = blockIdx.x * blockDim.x + threadIdx.x;
    if (e >= Etot) return;
    int src, dst;
    if (e < E) { src = ei[e]; dst = ei[E + e]; }
    else       { src = e - E; dst = src; }
    int pos = rowptr[dst] + atomicAdd(&cur[dst], 1);
    esrc[pos] = src;
}

// ---------- fused triple linear: 3 outputs share one input staging ----------
template <int K, int M>
__global__ void linear3_k(const float* __restrict__ A,
                          const float* __restrict__ W0, const float* __restrict__ b0,
                          const float* __restrict__ W1, const float* __restrict__ b1,
                          const float* __restrict__ W2, const float* __restrict__ b2,
                          float* __restrict__ o0, float* __restrict__ o1,
                          float* __restrict__ o2, int nrows) {
    constexpr int ROWS = 32;
    constexpr int NG = 256 / M;
    constexpr int RPT = ROWS / NG;
    __shared__ float lds[ROWS * K];
    int row0 = blockIdx.x * ROWS;
    int t = threadIdx.x;
    for (int idx = t; idx < ROWS * K / 4; idx += 256) {
        int r = idx / (K / 4), c4 = idx % (K / 4);
        int row = row0 + r;
        float4 v = make_float4(0.f, 0.f, 0.f, 0.f);
        if (row < nrows) v = *reinterpret_cast<const float4*>(&A[(long)row * K + c4 * 4]);
        *reinterpret_cast<float4*>(&lds[r * K + c4 * 4]) = v;
    }
    __syncthreads();
    int c = t % M, g = t / M;
    float a0[RPT], a1[RPT], a2[RPT];
    float bv0 = b0[c], bv1 = b1[c], bv2 = b2[c];
#pragma unroll
    for (int r = 0; r < RPT; ++r) { a0[r] = bv0; a1[r] = bv1; a2[r] = bv2; }
    for (int k = 0; k < K; ++k) {
        float w0 = W0[k * M + c], w1 = W1[k * M + c], w2 = W2[k * M + c];
#pragma unroll
        for (int r = 0; r < RPT; ++r) {
            float xv = lds[(g * RPT + r) * K + k];
            a0[r] += xv * w0; a1[r] += xv * w1; a2[r] += xv * w2;
        }
    }
#pragma unroll
    for (int r = 0; r < RPT; ++r) {
        int row = row0 + g * RPT + r;
        if (row < nrows) {
            o0[(long)row * M + c] = a0[r];
            o1[(long)row * M + c] = a1[r];
            o2[(long)row * M + c] = a2[r];
        }
    }
}

// ---------- fused GAT layer (online softmax over CSR in-edges) ----------
// layer1: F=128, 4 heads of 32; 128 threads per node, 2 nodes per block
__global__ void gat1_k(const float* __restrict__ xl, const float* __restrict__ xr,
                       const float* __restrict__ att, const int* __restrict__ rowptr,
                       const int* __restrict__ esrc, float* __restrict__ outp, int N) {
    int node = blockIdx.x * 2 + (threadIdx.x >> 7);
    if (node >= N) return;
    int f = threadIdx.x & 127;
    float xrf = xr[(long)node * 128 + f];
    float af = att[f];
    int s = rowptr[node], e = rowptr[node + 1];
    float m = -INFINITY, den = 0.f, acc = 0.f;
    for (int i = s; i < e; ++i) {
        int srcn = esrc[i];
        float xlv = xl[(long)srcn * 128 + f];
        float v = xlv + xrf;
        v = (v > 0.f) ? v : 0.2f * v;
        v *= af;
#pragma unroll
        for (int off = 16; off > 0; off >>= 1) v += __shfl_xor(v, off, 32);
        float nm = fmaxf(m, v);
        float sc = __expf(m - nm);
        float p  = __expf(v - nm);
        den = den * sc + p;
        acc = acc * sc + p * xlv;
        m = nm;
    }
    outp[(long)node * 128 + f] = acc / den;
}

// layer2: F=32, 1 head; 32 threads per node, 8 nodes per block
__global__ void gat2_k(const float* __restrict__ xl, const float* __restrict__ xr,
                       const float* __restrict__ att, const int* __restrict__ rowptr,
                       const int* __restrict__ esrc, float* __restrict__ outp, int N) {
    int node = blockIdx.x * 8 + (threadIdx.x >> 5);
    if (node >= N) return;
    int f = threadIdx.x & 31;
    float xrf = xr[(long)node * 32 + f];
    float af = att[f];
    int s = rowptr[node], e = rowptr[node + 1];
    float m = -INFINITY, den = 0.f, acc = 0.f;
    for (int i = s; i < e; ++i) {
        int srcn = esrc[i];
        float xlv = xl[(long)srcn * 32 + f];
        float v = xlv + xrf;
        v = (v > 0.f) ? v : 0.2f * v;
        v *= af;
#pragma unroll
        for (int off = 16; off > 0; off >>= 1) v += __shfl_xor(v, off, 32);
        float nm = fmaxf(m, v);
        float sc = __expf(m - nm);
        float p  = __expf(v - nm);
        den = den * sc + p;
        acc = acc * sc + p * xlv;
        m = nm;
    }
    outp[(long)node * 32 + f] = acc / den;
}

// ---------- graph norm stats (single pass: sum + sumsq) ----------
__global__ void gn_stats_k(const float* __restrict__ x, const float* __restrict__ bias,
                           const float* __restrict__ ms, const int* __restrict__ seg, int F,
                           float* __restrict__ meanp, float* __restrict__ istdp) {
    int g = blockIdx.x, f = threadIdx.x;
    int s = seg[g], e = seg[g + 1];
    int count = e - s;
    float cnt = (float)max(count, 1);
    float bv = bias[f];
    float s1 = 0.f, s2 = 0.f;
    for (int n = s; n < e; ++n) {
        float v = x[(long)n * F + f] + bv;
        s1 += v;
        s2 += v * v;
    }
    float mean = s1 / cnt;
    float mms = mean * ms[f];
    float var = s2 / cnt - 2.f * mms * mean + mms * mms;
    meanp[(long)g * F + f] = mean;
    istdp[(long)g * F + f] = 1.0f / sqrtf(var + EPS);
}

// ---------- graph norm apply + residual + exact GELU ----------
template <int F>
__global__ void gn_apply_k(const float* __restrict__ x, const float* __restrict__ bias,
                           const int* __restrict__ batch, const float* __restrict__ meanp,
                           const float* __restrict__ istdp, const float* __restrict__ w,
                           const float* __restrict__ b, const float* __restrict__ ms,
                           const float* __restrict__ res, float* __restrict__ h, long total) {
    long i = (long)blockIdx.x * blockDim.x + threadIdx.x;
    if (i >= total) return;
    int n = (int)(i / F), f = (int)(i % F);
    int g = batch[n];
    float xv = x[i] + bias[f];
    float o = w[f] * (xv - meanp[(long)g * F + f] * ms[f]) * istdp[(long)g * F + f] + b[f];
    h[i] = gelu_exact(o + res[i]);
}

// ---------- pooling + ego gate + MLP head (one block per graph) ----------
__global__ void pool_head_k(const float* __restrict__ h2, const int* __restrict__ seg,
                            const float* __restrict__ Weg, const float* __restrict__ beg,
                            const float* __restrict__ Wf1, const float* __restrict__ bf1,
                            const float* __restrict__ Wf2, const float* __restrict__ bf2,
                            float* __restrict__ outp) {
    int g = blockIdx.x, t = threadIdx.x;
    int s = seg[g], epos = seg[g + 1];
    int count = epos - s;
    __shared__ float ssum[8][32];
    __shared__ float smax[8][32];
    __shared__ float xfinal[96];
    __shared__ float emb[32];
    int f = t % 32, j = t / 32;
    float sum = 0.f, mx = -INFINITY;
    for (int n = s + j; n < epos; n += 8) {
        float v = h2[(long)n * 32 + f];
        sum += v;
        mx = fmaxf(mx, v);
    }
    ssum[j][f] = sum;
    smax[j][f] = mx;
    __syncthreads();
    if (t < 32) {
        float acs = 0.f, acm = -INFINITY;
        for (int jj = 0; jj < 8; ++jj) { acs += ssum[jj][t]; acm = fmaxf(acm, smax[jj][t]); }
        float mean = acs / (float)max(count, 1);
        float mxv = (count > 0) ? acm : 0.0f;
        xfinal[t] = mean;
        smax[0][t] = mxv;
    }
    __syncthreads();
    if (t < 64) {
        float acc = beg[t];
        for (int k = 0; k < 32; ++k) acc += xfinal[k] * Weg[k * 64 + t];
        float gate = 1.0f / (1.0f + expf(-acc));
        float val = (t < 32) ? xfinal[t] : smax[0][t - 32];
        xfinal[32 + t] = gate * val;
    }
    __syncthreads();
    if (t < 32) {
        float acc = bf1[t];
        for (int k = 0; k < 96; ++k) acc += xfinal[k] * Wf1[k * 32 + t];
        emb[t] = gelu_exact(acc);
    }
    __syncthreads();
    if (t < 32) {
        float v = emb[t] * Wf2[t];
#pragma unroll
        for (int off = 16; off > 0; off >>= 1) v += __shfl_xor(v, off, 32);
        if (t == 0) outp[g] = v + bf2[0];
    }
}

// ---------- launcher ----------
extern "C" void kernel_launch(void* const* d_in, const int* in_sizes, int n_in, void* d_out,
                              int out_size, void* d_ws, size_t ws_size, hipStream_t stream) {
    const float* x      = (const float*)d_in[0];
    const int*   ei     = (const int*)d_in[1];
    const int*   batch  = (const int*)d_in[2];
    const float* Wl1    = (const float*)d_in[3];
    const float* bl1    = (const float*)d_in[4];
    const float* Wr1    = (const float*)d_in[5];
    const float* br1    = (const float*)d_in[6];
    const float* att1   = (const float*)d_in[7];
    const float* bias1  = (const float*)d_in[8];
    const float* gn1_w  = (const float*)d_in[9];
    const float* gn1_b  = (const float*)d_in[10];
    const float* gn1_ms = (const float*)d_in[11];
    const float* Wl2    = (const float*)d_in[12];
    const float* bl2    = (const float*)d_in[13];
    const float* Wr2    = (const float*)d_in[14];
    const float* br2    = (const float*)d_in[15];
    const float* att2   = (const float*)d_in[16];
    const float* bias2  = (const float*)d_in[17];
    const float* gn2_w  = (const float*)d_in[18];
    const float* gn2_b  = (const float*)d_in[19];
    const float* gn2_ms = (const float*)d_in[20];
    const float* Wp1    = (const float*)d_in[21];
    const float* bp1    = (const float*)d_in[22];
    const float* Wp2    = (const float*)d_in[23];
    const float* bp2    = (const float*)d_in[24];
    const float* Weg    = (const float*)d_in[25];
    const float* beg    = (const float*)d_in[26];
    const float* Wf1    = (const float*)d_in[27];
    const float* bf1    = (const float*)d_in[28];
    const float* Wf2    = (const float*)d_in[29];
    const float* bf2    = (const float*)d_in[30];
    float* outp = (float*)d_out;

    const int N = in_sizes[2];
    const int E = in_sizes[1] / 2;
    const int Etot = E + N;
    const int G = out_size;
    constexpr int HC = 128, C = 32;

    char* ws = (char*)d_ws;
    size_t off = 0;
    auto alloc = [&](size_t bytes) -> void* {
        void* p = ws + off;
        off += (bytes + 255) & ~(size_t)255;
        return p;
    };
    int*   seg    = (int*)alloc((size_t)(G + 1) * 4);
    int*   cnt    = (int*)alloc((size_t)N * 4);
    int*   cur    = (int*)alloc((size_t)N * 4);
    int*   rowptr = (int*)alloc((size_t)(N + 1) * 4);
    int*   esrc   = (int*)alloc((size_t)Etot * 4);
    float* xl1    = (float*)alloc((size_t)N * HC * 4);
    float* xr1    = (float*)alloc((size_t)N * HC * 4);
    float* res1   = (float*)alloc((size_t)N * HC * 4);
    float* out1   = (float*)alloc((size_t)N * HC * 4);
    float* mean1  = (float*)alloc((size_t)G * HC * 4);
    float* istd1  = (float*)alloc((size_t)G * HC * 4);
    float* xl2    = (float*)alloc((size_t)N * C * 4);
    float* xr2    = (float*)alloc((size_t)N * C * 4);
    float* res2   = (float*)alloc((size_t)N * C * 4);
    float* out2   = (float*)alloc((size_t)N * C * 4);
    float* h2     = (float*)alloc((size_t)N * C * 4);
    float* mean2  = (float*)alloc((size_t)G * C * 4);
    float* istd2  = (float*)alloc((size_t)G * C * 4);
    float* h1     = xl1;  // alias: xl1 dead after gat1_k
    (void)ws_size; (void)n_in;

    // init + CSR build
    seg_bounds_k<<<(N + 255) / 256, 256, 0, stream>>>(batch, N, G, seg);
    hipMemsetAsync(cnt, 0, (size_t)N * 4, stream);
    hipMemsetAsync(cur, 0, (size_t)N * 4, stream);
    hist_k<<<(Etot + 255) / 256, 256, 0, stream>>>(ei, E, Etot, cnt);
    scan_k<<<1, 1024, 0, stream>>>(cnt, N, rowptr);
    scatter_k<<<(Etot + 255) / 256, 256, 0, stream>>>(ei, E, Etot, rowptr, cur, esrc);

    // ---- layer 1 ----
    int gblk = (N + 31) / 32;
    linear3_k<128, 128><<<gblk, 256, 0, stream>>>(x, Wl1, bl1, Wr1, br1, Wp1, bp1,
                                                  xl1, xr1, res1, N);
    gat1_k<<<(N + 1) / 2, 256, 0, stream>>>(xl1, xr1, att1, rowptr, esrc, out1, N);
    gn_stats_k<<<G, 128, 0, stream>>>(out1, bias1, gn1_ms, seg, 128, mean1, istd1);
    gn_apply_k<128><<<(int)(((long)N * 128 + 255) / 256), 256, 0, stream>>>(
        out1, bias1, batch, mean1, istd1, gn1_w, gn1_b, gn1_ms, res1, h1, (long)N * 128);

    // ---- layer 2 ----
    linear3_k<128, 32><<<gblk, 256, 0, stream>>>(h1, Wl2, bl2, Wr2, br2, Wp2, bp2,
                                                 xl2, xr2, res2, N);
    gat2_k<<<(N + 7) / 8, 256, 0, stream>>>(xl2, xr2, att2, rowptr, esrc, out2, N);
    gn_stats_k<<<G, 32, 0, stream>>>(out2, bias2, gn2_ms, seg, 32, mean2, istd2);
    gn_apply_k<32><<<(int)(((long)N * 32 + 255) / 256), 256, 0, stream>>>(
        out2, bias2, batch, mean2, istd2, gn2_w, gn2_b, gn2_ms, res2, h2, (long)N * 32);

    // ---- pooling + gate + head ----
    pool_head_k<<<G, 256, 0, stream>>>(h2, seg, Weg, beg, Wf1, bf1, Wf2, bf2, outp);
}

// Round 4
// 621.494 us; speedup vs baseline: 2.1799x; 1.2812x over previous
//
#include <hip/hip_runtime.h>
#include <math.h>

#define EPS 1e-5f

__device__ __forceinline__ float gelu_exact(float v) {
    return 0.5f * v * (1.0f + erff(v * 0.70710678118654752f));
}

// ---------- segment boundaries from sorted batch ----------
__global__ void seg_bounds_k(const int* __restrict__ batch, int N, int G, int* __restrict__ seg) {
    int i = blockIdx.x * blockDim.x + threadIdx.x;
    if (i >= N) return;
    int b = batch[i];
    if (i == 0) {
        for (int g = 0; g <= b; ++g) seg[g] = 0;
    } else {
        int pb = batch[i - 1];
        for (int g = pb + 1; g <= b; ++g) seg[g] = i;
    }
    if (i == N - 1) {
        for (int g = b + 1; g <= G; ++g) seg[g] = N;
    }
}

// ---------- CSR build ----------
__global__ void hist_k(const int* __restrict__ ei, int E, int Etot, int* __restrict__ cnt) {
    int e = blockIdx.x * blockDim.x + threadIdx.x;
    if (e >= Etot) return;
    int dst = (e < E) ? ei[E + e] : (e - E);
    atomicAdd(&cnt[dst], 1);
}

__global__ void scan_k(const int* __restrict__ cnt, int N, int* __restrict__ rowptr) {
    __shared__ int ts[1024];
    int t = threadIdx.x;
    int chunk = (N + 1023) / 1024;
    int s0 = t * chunk;
    int e0 = min(s0 + chunk, N);
    int sum = 0;
    for (int i = s0; i < e0; ++i) sum += cnt[i];
    ts[t] = sum;
    __syncthreads();
    for (int off = 1; off < 1024; off <<= 1) {
        int v = (t >= off) ? ts[t - off] : 0;
        __syncthreads();
        ts[t] += v;
        __syncthreads();
    }
    int run = (t > 0) ? ts[t - 1] : 0;
    for (int i = s0; i < e0; ++i) {
        rowptr[i] = run;
        run += cnt[i];
    }
    if (t == 1023) rowptr[N] = ts[1023];
}

__global__ void scatter_k(const int* __restrict__ ei, int E, int Etot,
                          const int* __restrict__ rowptr, int* __restrict__ cur,
                          int* __restrict__ esrc) {
    int e = blockIdx.x * blockDim.x + threadIdx.x;
    if (e >= Etot) return;
    int src, dst;
    if (e < E) { src = ei[e]; dst = ei[E + e]; }
    else       { src = e - E; dst = src; }
    int pos = rowptr[dst] + atomicAdd(&cur[dst], 1);
    esrc[pos] = src;
}

// ---------- fused triple linear ----------
template <int K, int M>
__global__ void linear3_k(const float* __restrict__ A,
                          const float* __restrict__ W0, const float* __restrict__ b0,
                          const float* __restrict__ W1, const float* __restrict__ b1,
                          const float* __restrict__ W2, const float* __restrict__ b2,
                          float* __restrict__ o0, float* __restrict__ o1,
                          float* __restrict__ o2, int nrows) {
    constexpr int ROWS = 32;
    constexpr int NG = 256 / M;
    constexpr int RPT = ROWS / NG;
    __shared__ float lds[ROWS * K];
    int row0 = blockIdx.x * ROWS;
    int t = threadIdx.x;
    for (int idx = t; idx < ROWS * K / 4; idx += 256) {
        int r = idx / (K / 4), c4 = idx % (K / 4);
        int row = row0 + r;
        float4 v = make_float4(0.f, 0.f, 0.f, 0.f);
        if (row < nrows) v = *reinterpret_cast<const float4*>(&A[(long)row * K + c4 * 4]);
        *reinterpret_cast<float4*>(&lds[r * K + c4 * 4]) = v;
    }
    __syncthreads();
    int c = t % M, g = t / M;
    float a0[RPT], a1[RPT], a2[RPT];
    float bv0 = b0[c], bv1 = b1[c], bv2 = b2[c];
#pragma unroll
    for (int r = 0; r < RPT; ++r) { a0[r] = bv0; a1[r] = bv1; a2[r] = bv2; }
    for (int k = 0; k < K; ++k) {
        float w0 = W0[k * M + c], w1 = W1[k * M + c], w2 = W2[k * M + c];
#pragma unroll
        for (int r = 0; r < RPT; ++r) {
            float xv = lds[(g * RPT + r) * K + k];
            a0[r] += xv * w0; a1[r] += xv * w1; a2[r] += xv * w2;
        }
    }
#pragma unroll
    for (int r = 0; r < RPT; ++r) {
        int row = row0 + g * RPT + r;
        if (row < nrows) {
            o0[(long)row * M + c] = a0[r];
            o1[(long)row * M + c] = a1[r];
            o2[(long)row * M + c] = a2[r];
        }
    }
}

// ---------- fused GAT layer 1: batch-4 online softmax (F=128, 4 heads) ----------
__global__ void __launch_bounds__(256) gat1_k(
        const float* __restrict__ xl, const float* __restrict__ xr,
        const float* __restrict__ att, const int* __restrict__ rowptr,
        const int* __restrict__ esrc, float* __restrict__ outp, int N) {
    int node = blockIdx.x * 2 + (threadIdx.x >> 7);
    if (node >= N) return;
    int f = threadIdx.x & 127;
    float xrf = xr[(long)node * 128 + f];
    float af = att[f];
    int s = rowptr[node], e = rowptr[node + 1];
    float m = -INFINITY, den = 0.f, acc = 0.f;
    int i = s;
    for (; i + 4 <= e; i += 4) {
        int s0 = esrc[i], s1 = esrc[i + 1], s2 = esrc[i + 2], s3 = esrc[i + 3];
        float x0 = xl[(long)s0 * 128 + f];
        float x1 = xl[(long)s1 * 128 + f];
        float x2 = xl[(long)s2 * 128 + f];
        float x3 = xl[(long)s3 * 128 + f];
        float v0 = x0 + xrf; v0 = ((v0 > 0.f) ? v0 : 0.2f * v0) * af;
        float v1 = x1 + xrf; v1 = ((v1 > 0.f) ? v1 : 0.2f * v1) * af;
        float v2 = x2 + xrf; v2 = ((v2 > 0.f) ? v2 : 0.2f * v2) * af;
        float v3 = x3 + xrf; v3 = ((v3 > 0.f) ? v3 : 0.2f * v3) * af;
#pragma unroll
        for (int off = 16; off > 0; off >>= 1) {
            v0 += __shfl_xor(v0, off, 32);
            v1 += __shfl_xor(v1, off, 32);
            v2 += __shfl_xor(v2, off, 32);
            v3 += __shfl_xor(v3, off, 32);
        }
        float vm = fmaxf(fmaxf(v0, v1), fmaxf(v2, v3));
        float nm = fmaxf(m, vm);
        float sc = __expf(m - nm);
        float p0 = __expf(v0 - nm), p1 = __expf(v1 - nm);
        float p2 = __expf(v2 - nm), p3 = __expf(v3 - nm);
        den = den * sc + ((p0 + p1) + (p2 + p3));
        acc = acc * sc + ((p0 * x0 + p1 * x1) + (p2 * x2 + p3 * x3));
        m = nm;
    }
    for (; i < e; ++i) {
        int srcn = esrc[i];
        float xlv = xl[(long)srcn * 128 + f];
        float v = xlv + xrf;
        v = ((v > 0.f) ? v : 0.2f * v) * af;
#pragma unroll
        for (int off = 16; off > 0; off >>= 1) v += __shfl_xor(v, off, 32);
        float nm = fmaxf(m, v);
        float sc = __expf(m - nm);
        float p  = __expf(v - nm);
        den = den * sc + p;
        acc = acc * sc + p * xlv;
        m = nm;
    }
    outp[(long)node * 128 + f] = acc / den;
}

// ---------- fused GAT layer 2: batch-4 online softmax (F=32, 1 head) ----------
__global__ void __launch_bounds__(256) gat2_k(
        const float* __restrict__ xl, const float* __restrict__ xr,
        const float* __restrict__ att, const int* __restrict__ rowptr,
        const int* __restrict__ esrc, float* __restrict__ outp, int N) {
    int node = blockIdx.x * 8 + (threadIdx.x >> 5);
    if (node >= N) return;
    int f = threadIdx.x & 31;
    float xrf = xr[(long)node * 32 + f];
    float af = att[f];
    int s = rowptr[node], e = rowptr[node + 1];
    float m = -INFINITY, den = 0.f, acc = 0.f;
    int i = s;
    for (; i + 4 <= e; i += 4) {
        int s0 = esrc[i], s1 = esrc[i + 1], s2 = esrc[i + 2], s3 = esrc[i + 3];
        float x0 = xl[(long)s0 * 32 + f];
        float x1 = xl[(long)s1 * 32 + f];
        float x2 = xl[(long)s2 * 32 + f];
        float x3 = xl[(long)s3 * 32 + f];
        float v0 = x0 + xrf; v0 = ((v0 > 0.f) ? v0 : 0.2f * v0) * af;
        float v1 = x1 + xrf; v1 = ((v1 > 0.f) ? v1 : 0.2f * v1) * af;
        float v2 = x2 + xrf; v2 = ((v2 > 0.f) ? v2 : 0.2f * v2) * af;
        float v3 = x3 + xrf; v3 = ((v3 > 0.f) ? v3 : 0.2f * v3) * af;
#pragma unroll
        for (int off = 16; off > 0; off >>= 1) {
            v0 += __shfl_xor(v0, off, 32);
            v1 += __shfl_xor(v1, off, 32);
            v2 += __shfl_xor(v2, off, 32);
            v3 += __shfl_xor(v3, off, 32);
        }
        float vm = fmaxf(fmaxf(v0, v1), fmaxf(v2, v3));
        float nm = fmaxf(m, vm);
        float sc = __expf(m - nm);
        float p0 = __expf(v0 - nm), p1 = __expf(v1 - nm);
        float p2 = __expf(v2 - nm), p3 = __expf(v3 - nm);
        den = den * sc + ((p0 + p1) + (p2 + p3));
        acc = acc * sc + ((p0 * x0 + p1 * x1) + (p2 * x2 + p3 * x3));
        m = nm;
    }
    for (; i < e; ++i) {
        int srcn = esrc[i];
        float xlv = xl[(long)srcn * 32 + f];
        float v = xlv + xrf;
        v = ((v > 0.f) ? v : 0.2f * v) * af;
#pragma unroll
        for (int off = 16; off > 0; off >>= 1) v += __shfl_xor(v, off, 32);
        float nm = fmaxf(m, v);
        float sc = __expf(m - nm);
        float p  = __expf(v - nm);
        den = den * sc + p;
        acc = acc * sc + p * xlv;
        m = nm;
    }
    outp[(long)node * 32 + f] = acc / den;
}

// ---------- graph norm stats: 2D block (F x NW), LDS reduce ----------
template <int F, int NW>
__global__ void gn_stats_k(const float* __restrict__ x, const float* __restrict__ bias,
                           const float* __restrict__ ms, const int* __restrict__ seg,
                           float* __restrict__ meanp, float* __restrict__ istdp) {
    __shared__ float s1s[NW][F];
    __shared__ float s2s[NW][F];
    int g = blockIdx.x;
    int f = threadIdx.x % F, j = threadIdx.x / F;
    int s = seg[g], e = seg[g + 1];
    int count = e - s;
    float bv = bias[f];
    float s1 = 0.f, s2 = 0.f;
    for (int n = s + j; n < e; n += NW) {
        float v = x[(long)n * F + f] + bv;
        s1 += v;
        s2 += v * v;
    }
    s1s[j][f] = s1;
    s2s[j][f] = s2;
    __syncthreads();
    if (j == 0) {
#pragma unroll
        for (int jj = 1; jj < NW; ++jj) { s1 += s1s[jj][f]; s2 += s2s[jj][f]; }
        float cnt = (float)max(count, 1);
        float mean = s1 / cnt;
        float mms = mean * ms[f];
        float var = s2 / cnt - 2.f * mms * mean + mms * mms;
        meanp[(long)g * F + f] = mean;
        istdp[(long)g * F + f] = 1.0f / sqrtf(var + EPS);
    }
}

// ---------- graph norm apply + residual + exact GELU (float4) ----------
template <int F>
__global__ void gn_apply_k(const float* __restrict__ x, const float* __restrict__ bias,
                           const int* __restrict__ batch, const float* __restrict__ meanp,
                           const float* __restrict__ istdp, const float* __restrict__ w,
                           const float* __restrict__ b, const float* __restrict__ ms,
                           const float* __restrict__ res, float* __restrict__ h, int N) {
    constexpr int F4 = F / 4;
    long i = (long)blockIdx.x * blockDim.x + threadIdx.x;
    if (i >= (long)N * F4) return;
    int n = (int)(i / F4), f4 = (int)(i % F4);
    int g = batch[n];
    long base = (long)n * F + f4 * 4;
    long gbase = (long)g * F + f4 * 4;
    float4 xv = *reinterpret_cast<const float4*>(&x[base]);
    float4 rv = *reinterpret_cast<const float4*>(&res[base]);
    float4 mv = *reinterpret_cast<const float4*>(&meanp[gbase]);
    float4 iv = *reinterpret_cast<const float4*>(&istdp[gbase]);
    float4 bv = *reinterpret_cast<const float4*>(&bias[f4 * 4]);
    float4 wv = *reinterpret_cast<const float4*>(&w[f4 * 4]);
    float4 bb = *reinterpret_cast<const float4*>(&b[f4 * 4]);
    float4 mw = *reinterpret_cast<const float4*>(&ms[f4 * 4]);
    float4 o;
    o.x = gelu_exact(wv.x * ((xv.x + bv.x) - mv.x * mw.x) * iv.x + bb.x + rv.x);
    o.y = gelu_exact(wv.y * ((xv.y + bv.y) - mv.y * mw.y) * iv.y + bb.y + rv.y);
    o.z = gelu_exact(wv.z * ((xv.z + bv.z) - mv.z * mw.z) * iv.z + bb.z + rv.z);
    o.w = gelu_exact(wv.w * ((xv.w + bv.w) - mv.w * mw.w) * iv.w + bb.w + rv.w);
    *reinterpret_cast<float4*>(&h[base]) = o;
}

// ---------- pooling + ego gate + MLP head ----------
__global__ void pool_head_k(const float* __restrict__ h2, const int* __restrict__ seg,
                            const float* __restrict__ Weg, const float* __restrict__ beg,
                            const float* __restrict__ Wf1, const float* __restrict__ bf1,
                            const float* __restrict__ Wf2, const float* __restrict__ bf2,
                            float* __restrict__ outp) {
    int g = blockIdx.x, t = threadIdx.x;
    int s = seg[g], epos = seg[g + 1];
    int count = epos - s;
    __shared__ float ssum[8][32];
    __shared__ float smax[8][32];
    __shared__ float xfinal[96];
    __shared__ float emb[32];
    int f = t % 32, j = t / 32;
    float sum = 0.f, mx = -INFINITY;
    for (int n = s + j; n < epos; n += 8) {
        float v = h2[(long)n * 32 + f];
        sum += v;
        mx = fmaxf(mx, v);
    }
    ssum[j][f] = sum;
    smax[j][f] = mx;
    __syncthreads();
    if (t < 32) {
        float acs = 0.f, acm = -INFINITY;
        for (int jj = 0; jj < 8; ++jj) { acs += ssum[jj][t]; acm = fmaxf(acm, smax[jj][t]); }
        float mean = acs / (float)max(count, 1);
        float mxv = (count > 0) ? acm : 0.0f;
        xfinal[t] = mean;
        smax[0][t] = mxv;
    }
    __syncthreads();
    if (t < 64) {
        float acc = beg[t];
        for (int k = 0; k < 32; ++k) acc += xfinal[k] * Weg[k * 64 + t];
        float gate = 1.0f / (1.0f + expf(-acc));
        float val = (t < 32) ? xfinal[t] : smax[0][t - 32];
        xfinal[32 + t] = gate * val;
    }
    __syncthreads();
    if (t < 32) {
        float acc = bf1[t];
        for (int k = 0; k < 96; ++k) acc += xfinal[k] * Wf1[k * 32 + t];
        emb[t] = gelu_exact(acc);
    }
    __syncthreads();
    if (t < 32) {
        float v = emb[t] * Wf2[t];
#pragma unroll
        for (int off = 16; off > 0; off >>= 1) v += __shfl_xor(v, off, 32);
        if (t == 0) outp[g] = v + bf2[0];
    }
}

// ---------- launcher ----------
extern "C" void kernel_launch(void* const* d_in, const int* in_sizes, int n_in, void* d_out,
                              int out_size, void* d_ws, size_t ws_size, hipStream_t stream) {
    const float* x      = (const float*)d_in[0];
    const int*   ei     = (const int*)d_in[1];
    const int*   batch  = (const int*)d_in[2];
    const float* Wl1    = (const float*)d_in[3];
    const float* bl1    = (const float*)d_in[4];
    const float* Wr1    = (const float*)d_in[5];
    const float* br1    = (const float*)d_in[6];
    const float* att1   = (const float*)d_in[7];
    const float* bias1  = (const float*)d_in[8];
    const float* gn1_w  = (const float*)d_in[9];
    const float* gn1_b  = (const float*)d_in[10];
    const float* gn1_ms = (const float*)d_in[11];
    const float* Wl2    = (const float*)d_in[12];
    const float* bl2    = (const float*)d_in[13];
    const float* Wr2    = (const float*)d_in[14];
    const float* br2    = (const float*)d_in[15];
    const float* att2   = (const float*)d_in[16];
    const float* bias2  = (const float*)d_in[17];
    const float* gn2_w  = (const float*)d_in[18];
    const float* gn2_b  = (const float*)d_in[19];
    const float* gn2_ms = (const float*)d_in[20];
    const float* Wp1    = (const float*)d_in[21];
    const float* bp1    = (const float*)d_in[22];
    const float* Wp2    = (const float*)d_in[23];
    const float* bp2    = (const float*)d_in[24];
    const float* Weg    = (const float*)d_in[25];
    const float* beg    = (const float*)d_in[26];
    const float* Wf1    = (const float*)d_in[27];
    const float* bf1    = (const float*)d_in[28];
    const float* Wf2    = (const float*)d_in[29];
    const float* bf2    = (const float*)d_in[30];
    float* outp = (float*)d_out;

    const int N = in_sizes[2];
    const int E = in_sizes[1] / 2;
    const int Etot = E + N;
    const int G = out_size;
    constexpr int HC = 128, C = 32;

    char* ws = (char*)d_ws;
    size_t off = 0;
    auto alloc = [&](size_t bytes) -> void* {
        void* p = ws + off;
        off += (bytes + 255) & ~(size_t)255;
        return p;
    };
    int*   seg    = (int*)alloc((size_t)(G + 1) * 4);
    int*   cnt    = (int*)alloc((size_t)N * 4);
    int*   cur    = (int*)alloc((size_t)N * 4);
    int*   rowptr = (int*)alloc((size_t)(N + 1) * 4);
    int*   esrc   = (int*)alloc((size_t)Etot * 4);
    float* xl1    = (float*)alloc((size_t)N * HC * 4);
    float* xr1    = (float*)alloc((size_t)N * HC * 4);
    float* res1   = (float*)alloc((size_t)N * HC * 4);
    float* out1   = (float*)alloc((size_t)N * HC * 4);
    float* mean1  = (float*)alloc((size_t)G * HC * 4);
    float* istd1  = (float*)alloc((size_t)G * HC * 4);
    float* xl2    = (float*)alloc((size_t)N * C * 4);
    float* xr2    = (float*)alloc((size_t)N * C * 4);
    float* res2   = (float*)alloc((size_t)N * C * 4);
    float* out2   = (float*)alloc((size_t)N * C * 4);
    float* h2     = (float*)alloc((size_t)N * C * 4);
    float* mean2  = (float*)alloc((size_t)G * C * 4);
    float* istd2  = (float*)alloc((size_t)G * C * 4);
    float* h1     = xl1;  // alias: xl1 dead after gat1_k
    (void)ws_size; (void)n_in;

    // init + CSR build
    seg_bounds_k<<<(N + 255) / 256, 256, 0, stream>>>(batch, N, G, seg);
    hipMemsetAsync(cnt, 0, (size_t)N * 4, stream);
    hipMemsetAsync(cur, 0, (size_t)N * 4, stream);
    hist_k<<<(Etot + 255) / 256, 256, 0, stream>>>(ei, E, Etot, cnt);
    scan_k<<<1, 1024, 0, stream>>>(cnt, N, rowptr);
    scatter_k<<<(Etot + 255) / 256, 256, 0, stream>>>(ei, E, Etot, rowptr, cur, esrc);

    // ---- layer 1 ----
    int gblk = (N + 31) / 32;
    linear3_k<128, 128><<<gblk, 256, 0, stream>>>(x, Wl1, bl1, Wr1, br1, Wp1, bp1,
                                                  xl1, xr1, res1, N);
    gat1_k<<<(N + 1) / 2, 256, 0, stream>>>(xl1, xr1, att1, rowptr, esrc, out1, N);
    gn_stats_k<128, 4><<<G, 512, 0, stream>>>(out1, bias1, gn1_ms, seg, mean1, istd1);
    gn_apply_k<128><<<(int)(((long)N * 32 + 255) / 256), 256, 0, stream>>>(
        out1, bias1, batch, mean1, istd1, gn1_w, gn1_b, gn1_ms, res1, h1, N);

    // ---- layer 2 ----
    linear3_k<128, 32><<<gblk, 256, 0, stream>>>(h1, Wl2, bl2, Wr2, br2, Wp2, bp2,
                                                 xl2, xr2, res2, N);
    gat2_k<<<(N + 7) / 8, 256, 0, stream>>>(xl2, xr2, att2, rowptr, esrc, out2, N);
    gn_stats_k<32, 16><<<G, 512, 0, stream>>>(out2, bias2, gn2_ms, seg, mean2, istd2);
    gn_apply_k<32><<<(int)(((long)N * 8 + 255) / 256), 256, 0, stream>>>(
        out2, bias2, batch, mean2, istd2, gn2_w, gn2_b, gn2_ms, res2, h2, N);

    // ---- pooling + gate + head ----
    pool_head_k<<<G, 256, 0, stream>>>(h2, seg, Weg, beg, Wf1, bf1, Wf2, bf2, outp);
}